// Round 4
// baseline (241.038 us; speedup 1.0000x reference)
//
#include <hip/hip_runtime.h>

#define NN 1024
#define HH 512
#define TR 32
#define TC 32
#define S1R 70          // stage-1 rows needed: 2*(TR-1)+8
#define ADS 36          // A/D plane stride: mult-of-4 -> b128-aligned; quad-group (9*row+cg)%8 uniform (free)

typedef float f2  __attribute__((ext_vector_type(2)));
typedef float f4v __attribute__((ext_vector_type(4)));

// acc.lo += ab.lo*w.lo ; acc.hi += ab.hi*w.lo   (broadcast LOW half of w)
__device__ __forceinline__ void pk_fma_blo(f2& acc, f2 ab, f2 w) {
    asm("v_pk_fma_f32 %0, %1, %2, %0 op_sel:[0,0,0] op_sel_hi:[1,0,1]"
        : "+v"(acc) : "v"(ab), "v"(w));
}
// acc.lo += ab.lo*w.hi ; acc.hi += ab.hi*w.hi   (broadcast HIGH half of w)
__device__ __forceinline__ void pk_fma_bhi(f2& acc, f2 ab, f2 w) {
    asm("v_pk_fma_f32 %0, %1, %2, %0 op_sel:[0,1,0] op_sel_hi:[1,1,1]"
        : "+v"(acc) : "v"(ab), "v"(w));
}

__global__ __launch_bounds__(256, 8) void dwt2d_fused(const float* __restrict__ x,
                                                      const float* __restrict__ bmt,
                                                      float* __restrict__ out) {
    // No Xs staging buffer: stage-1 reads its windows straight from global
    // (contiguous axis; halo overlap between lanes is L1/L2-served, input L3-fits).
    __shared__ float As[S1R][ADS];   // 70 x 36 x 4B = 10,080 B
    __shared__ float Ds[S1R][ADS];   // 70 x 36 x 4B = 10,080 B  (total 20,160 -> 8 blk/CU, 32 waves)

    const int tid = threadIdx.x;
    const int b  = blockIdx.z;                 // default mapping: vertical halo neighbors
    const int R0 = blockIdx.y * TR;            // (g±16) are already same-XCD (16 % 8 == 0)
    const int C0 = blockIdx.x * TC;

    // lohi[j] = (dec_lo[j], dec_hi[j]); dec_lo[j]=bmt[7-j], dec_hi[j]=bmt[j]*(j odd ? +1 : -1)
    f2 lohi[8];
#pragma unroll
    for (int j = 0; j < 8; ++j) {
        float l = bmt[7 - j];
        float v = bmt[j];
        f2 p; p.x = l; p.y = (j & 1) ? v : -v;
        lohi[j] = p;
    }

    const float* xb = x + (size_t)b * NN * NN;
    const int rbase = 2 * R0 - 3;              // stage-1 row u -> x row (rbase+u) & 1023

    // ---- phase 1+2 fused: stage-1 filter along x rows, direct from global.
    // Output (u, c): a/d[c] = sum_j w[j] * x[ru][2(C0+c)-3+j].  For a group of 4
    // outputs c0..c0+3 the taps are floats s..s+13, s = 2C0+2c0-3 (odd).
    // Load 4 aligned float4s at bc = s-1 (bc % 4 == 0): f[0..15], window = f[1..14].
    for (int pos = tid; pos < S1R * 8; pos += 256) {
        int u  = pos >> 3;
        int c0 = (pos & 7) * 4;
        int ru = (rbase + u) & (NN - 1);
        const float* xr = xb + ((size_t)ru << 10);
        int bc = 2 * C0 + 2 * c0 - 4;          // 16B-aligned; wrap each f4 via &1023
        float f[16];
#pragma unroll
        for (int i = 0; i < 4; ++i) {
            f4v t = *(const f4v*)(xr + ((bc + 4 * i) & (NN - 1)));
            f[4 * i + 0] = t.x; f[4 * i + 1] = t.y; f[4 * i + 2] = t.z; f[4 * i + 3] = t.w;
        }
        f2 w2[7];
#pragma unroll
        for (int t = 0; t < 7; ++t) { f2 p; p.x = f[2 * t + 1]; p.y = f[2 * t + 2]; w2[t] = p; }
        f2 accs[4];
#pragma unroll
        for (int m = 0; m < 4; ++m) {
            f2 acc; acc.x = 0.f; acc.y = 0.f;
#pragma unroll
            for (int s = 0; s < 4; ++s) {
                pk_fma_blo(acc, lohi[2 * s],     w2[m + s]);   // j=2s   tap (w.x)
                pk_fma_bhi(acc, lohi[2 * s + 1], w2[m + s]);   // j=2s+1 tap (w.y)
            }
            accs[m] = acc;
        }
        f4v va, vd;
        va.x = accs[0].x; va.y = accs[1].x; va.z = accs[2].x; va.w = accs[3].x;
        vd.x = accs[0].y; vd.y = accs[1].y; vd.z = accs[2].y; vd.w = accs[3].y;
        *(f4v*)&As[u][c0] = va;                // b128, quad-group (9u+cg)%8 distinct per octet -> free
        *(f4v*)&Ds[u][c0] = vd;
    }
    __syncthreads();                           // the ONLY barrier

    // ---- phase 3: stage-2 filter (along rows); 4 quadrants. One b128 per plane per tap.
    const int cg = tid & 7;
    const int r  = tid >> 3;
    f2 acc0[4], acc1[4];                       // acc0[i]=(aa,ad), acc1[i]=(da,dd)
#pragma unroll
    for (int i = 0; i < 4; ++i) {
        acc0[i].x = 0.f; acc0[i].y = 0.f;
        acc1[i].x = 0.f; acc1[i].y = 0.f;
    }
#pragma unroll
    for (int j = 0; j < 8; ++j) {
        f4v qa = *(const f4v*)&As[2 * r + j][4 * cg];   // quad-group (2r+j+cg)%8 uniform -> free
        f4v qd = *(const f4v*)&Ds[2 * r + j][4 * cg];
        f2 lh = lohi[j];
        f2 a01 = qa.xy, a23 = qa.zw, d01 = qd.xy, d23 = qd.zw;
        pk_fma_blo(acc0[0], lh, a01);   // (aa,ad) += (lo,hi)*A[..][4cg+0]
        pk_fma_bhi(acc0[1], lh, a01);
        pk_fma_blo(acc0[2], lh, a23);
        pk_fma_bhi(acc0[3], lh, a23);
        pk_fma_blo(acc1[0], lh, d01);   // (da,dd) += (lo,hi)*D[..][4cg+0]
        pk_fma_bhi(acc1[1], lh, d01);
        pk_fma_blo(acc1[2], lh, d23);
        pk_fma_bhi(acc1[3], lh, d23);
    }
    float* ob = out + (size_t)b * NN * NN;
    const int orow = R0 + r;
    const int ocol = C0 + 4 * cg;
    f4v s0; s0.x = acc0[0].x; s0.y = acc0[1].x; s0.z = acc0[2].x; s0.w = acc0[3].x;
    f4v s1; s1.x = acc0[0].y; s1.y = acc0[1].y; s1.z = acc0[2].y; s1.w = acc0[3].y;
    f4v s2; s2.x = acc1[0].x; s2.y = acc1[1].x; s2.z = acc1[2].x; s2.w = acc1[3].x;
    f4v s3; s3.x = acc1[0].y; s3.y = acc1[1].y; s3.z = acc1[2].y; s3.w = acc1[3].y;
    *(f4v*)(ob + (size_t)orow * NN + ocol)             = s0;   // normal stores (NT reverted)
    *(f4v*)(ob + (size_t)orow * NN + ocol + HH)        = s1;
    *(f4v*)(ob + (size_t)(orow + HH) * NN + ocol)      = s2;
    *(f4v*)(ob + (size_t)(orow + HH) * NN + ocol + HH) = s3;
}

extern "C" void kernel_launch(void* const* d_in, const int* in_sizes, int n_in,
                              void* d_out, int out_size, void* d_ws, size_t ws_size,
                              hipStream_t stream) {
    const float* x   = (const float*)d_in[0];
    const float* bmt = (const float*)d_in[1];
    float* out = (float*)d_out;
    const int B = in_sizes[0] / (NN * NN);   // 32
    dim3 grid(HH / TC, HH / TR, B);          // 16 x 16 x 32
    dwt2d_fused<<<grid, 256, 0, stream>>>(x, bmt, out);
}